// Round 9
// baseline (229.368 us; speedup 1.0000x reference)
//
#include <hip/hip_runtime.h>
#include <math.h>

// Focal_loss2 — single fused dispatch. R8: async global_load_lds-staged LDS
// tiles (kills the 64KB-plane-stride L1 set-aliasing + register-batched
// staging that capped R1-R7), R4 rolling y-march compute from LDS, R7 XCD
// swizzle.
//   neg: w = sigmoid(x)^2 * (gt==-1) * (x is 3x3x3 local max); loss += softplus(x)*w
//        local-max test in logit space (monotone sigmoid; validated R3-R7, absmax 0.0)
//   pos: 64 coords/batch/level gather; w1=(1-sigmoid)^2; per-(b,tag) min of w1
// ws (floats): [0]=lossneg_a [1]=wneg_a [2]=lossneg_b [3]=wneg_b
//              [4]=losspos_a [5]=cntpos_a [6]=losspos_b [7]=cntpos_b [8]=block counter
// out: [0]=cls_loss_pos [1]=cls_loss_neg [2]=count_pos [3]=count_neg
//      [4]=wsum_pos [5]=wsum_neg [6..37]=pred_prob_min[2][B=2][T=8]

#define NBLK_A 2048   // 4 vol x 16 z-slabs(8 z) x 32 y-chunks(4 y)
#define NBLK_B 256    // 4 vol x  4 z-slabs(16 z) x 16 y-chunks(4 y)
#define NBLK_TOTAL (NBLK_A + NBLK_B + 1)

__device__ __forceinline__ float fmax3(float a, float b, float c) {
    return fmaxf(a, fmaxf(b, c));
}

// async 16B global->LDS DMA (no VGPR round trip; vmcnt-counted).
// LDS side is wave-uniform base + lane*16: our staging index u = i*256 + t is
// lane-contiguous, so tile[u*4] satisfies the layout rule (m104/m108 caveat).
__device__ __forceinline__ void load_lds_16(const float* g, float* l) {
    __builtin_amdgcn_global_load_lds(
        (const __attribute__((address_space(1))) void*)g,
        (__attribute__((address_space(3))) void*)l,
        16, 0, 0);
}

// Tile: RZ z-planes x 6 y-rows x D floats, row r = rz*6+ry (lane-contiguous
// staging order). Interior: ZI z x 4 y. Each thread (xq, zi) computes 4 output
// rows via rolling y-march over 6 steps, 3 ds_read_b128 per step. x-halo via
// wave shuffle on the z-folded column max (xq in low lane bits; group edges
// use the clamp override). y/z boundary via index clamping at staging time
// (duplicates an in-window value -> max unchanged).
template <int D, int LOG2D, int XQ, int RZ, int ZI>
__device__ __forceinline__ void neg_tile(
    const float* __restrict__ logits, const float* __restrict__ gt,
    float* __restrict__ tile, int vol, int z0, int y0, int t,
    float& loss, float& wsum)
{
    constexpr int QPR = D >> 2;           // quads per row
    constexpr int QPR_SH = LOG2D - 2;
    constexpr int NROWS = RZ * 6;
    constexpr int NQ = NROWS * QPR;       // total staged quads
    constexpr int ITERS = (NQ + 255) / 256;
    const float* vb = logits + (vol << (3 * LOG2D));

    // ---- async stage: all DMAs issued back-to-back, zero VGPR pressure ----
#pragma unroll
    for (int i = 0; i < ITERS; ++i) {
        int u = i * 256 + t;
        if (u < NQ) {                      // NQ multiple of 64: wave-uniform
            int r = u >> QPR_SH;
            int q = u & (QPR - 1);
            int rz = r / 6;
            int ry = r - rz * 6;
            int gz = z0 - 1 + rz; gz = gz < 0 ? 0 : (gz > D - 1 ? D - 1 : gz);
            int gy = y0 - 1 + ry; gy = gy < 0 ? 0 : (gy > D - 1 ? D - 1 : gy);
            load_lds_16(vb + (gz << (2 * LOG2D)) + (gy << LOG2D) + (q << 2),
                        tile + u * 4);
        }
    }

    // ---- gt quads: direct global (streamed once, no reuse) ----
    const int xq = t & (XQ - 1);
    const int zi = t / XQ;                 // 0..ZI-1
    const int x0 = xq << 2;
    const float* pg = gt + (vol << (3 * LOG2D)) + ((z0 + zi) << (2 * LOG2D)) + x0;
    float4 gq[4];
#pragma unroll
    for (int j = 0; j < 4; ++j)
        gq[j] = *(const float4*)(pg + ((y0 + j) << LOG2D));

    __syncthreads();   // drains vmcnt(0): staged tile + gt both ready

    // ---- compute: rolling y-march from LDS ----
    const float* tz0 = tile + ((zi + 0) * 6) * D + x0;
    const float* tz1 = tile + ((zi + 1) * 6) * D + x0;
    const float* tz2 = tile + ((zi + 2) * 6) * D + x0;
    float zw[3][4];   // ring: per-row column max over the 3 z-planes
    float cc[2][4];   // ring: center-plane raw values
#pragma unroll
    for (int s = 0; s < 6; ++s) {
        float4 a0 = *(const float4*)(tz0 + s * D);
        float4 a1 = *(const float4*)(tz1 + s * D);
        float4 a2 = *(const float4*)(tz2 + s * D);
        zw[s % 3][0] = fmax3(a0.x, a1.x, a2.x);
        zw[s % 3][1] = fmax3(a0.y, a1.y, a2.y);
        zw[s % 3][2] = fmax3(a0.z, a1.z, a2.z);
        zw[s % 3][3] = fmax3(a0.w, a1.w, a2.w);
        cc[s & 1][0] = a1.x; cc[s & 1][1] = a1.y;
        cc[s & 1][2] = a1.z; cc[s & 1][3] = a1.w;
        if (s >= 2) {
            float cz0 = fmax3(zw[0][0], zw[1][0], zw[2][0]);
            float cz1 = fmax3(zw[0][1], zw[1][1], zw[2][1]);
            float cz2 = fmax3(zw[0][2], zw[1][2], zw[2][2]);
            float cz3 = fmax3(zw[0][3], zw[1][3], zw[2][3]);
            float lco = __shfl_up(cz3, 1);   if (xq == 0)      lco = cz0;
            float rco = __shfl_down(cz0, 1); if (xq == XQ - 1) rco = cz3;
            float m0 = fmax3(lco, cz0, cz1);
            float m1 = fmax3(cz0, cz1, cz2);
            float m2 = fmax3(cz1, cz2, cz3);
            float m3 = fmax3(cz2, cz3, rco);
            const float* c = cc[(s - 1) & 1];
            float4 gv = gq[s - 2];
            float ms[4] = {m0, m1, m2, m3};
            float gs[4] = {gv.x, gv.y, gv.z, gv.w};
#pragma unroll
            for (int k = 0; k < 4; ++k) {
                if (gs[k] == -1.0f && ms[k] == c[k]) {
                    float e = __expf(c[k]);                  // e^x
                    float u = __builtin_amdgcn_rcpf(1.0f + e);
                    float sc = e * u;                        // sigmoid(x)
                    float wv = sc * sc;
                    wsum += wv;
                    loss += (-__logf(u)) * wv;               // softplus(x)
                }
            }
        }
    }
}

__global__ __launch_bounds__(256, 4) void fused_kernel(
    const float* __restrict__ la, const float* __restrict__ lb,
    const float* __restrict__ ga, const float* __restrict__ gb,
    const int* __restrict__ conn_a, const int* __restrict__ conn_b,
    const int* __restrict__ coord_a, const int* __restrict__ coord_b,
    float* __restrict__ ws, float* __restrict__ out)
{
    __shared__ float tile[7680];   // 30 KB: level-a 10z x 6y x 128 (b: 18x6x64)
    __shared__ float sred[8];
    const int bid = blockIdx.x;
    const int t = threadIdx.x;
    float loss = 0.0f, wsum = 0.0f;
    int accIdx = -1;

    if (bid < NBLK_A) {
        // level a: D=128, interior 8z x 4y. XCD swizzle (R7): xcd = bid&7 owns
        // z-slabs {xcd, xcd+8} per vol, y swept fastest.
        accIdx = 0;
        const int c = bid & 7;
        const int g = bid >> 3;        // 0..255
        const int yc = g & 31;
        const int j = g >> 5;          // 0..7 = vol(4) x slab-half(2)
        const int vol = j >> 1;
        const int zb = ((j & 1) << 3) | c;
        neg_tile<128, 7, 32, 10, 8>(la, ga, tile, vol, zb * 8, yc * 4, t,
                                    loss, wsum);
    } else if (bid < NBLK_A + NBLK_B) {
        // level b: D=64, interior 16z x 4y, swizzled likewise.
        accIdx = 2;
        const int b2 = bid - NBLK_A;
        const int c = b2 & 7;
        const int g = b2 >> 3;         // 0..31
        const int yc = g & 15;
        const int j = g >> 4;          // 0..1
        const int unit = c * 2 + j;    // 0..15 = vol(4) x zb(4)
        const int vol = unit >> 2;
        const int zb = unit & 3;
        neg_tile<64, 6, 16, 18, 16>(lb, gb, tile, vol, zb * 16, yc * 4, t,
                                    loss, wsum);
    } else {
        // pos block: both levels, 128 active threads (tile reused as scratch)
        float* w1s = tile;
        float* tgf = tile + 128;
        for (int level = 0; level < 2; ++level) {
            const float* logits = level ? lb : la;
            const int* conn = level ? conn_b : conn_a;
            const int* coord = level ? coord_b : coord_a;
            const int D = level ? 64 : 128;
            float li = 0.0f, ci = 0.0f;
            if (t < 128) {
                const int* c4 = coord + t * 4;
                int a = c4[0], zz = c4[1], yy = c4[2], xx = c4[3];
                bool valid = a > -1;
                int aa = valid ? a : 0, z2 = valid ? zz : 0,
                    y2 = valid ? yy : 0, x2 = valid ? xx : 0;
                int b = t >> 6;
                int off = (((b * 2 + aa) * D + z2) * D + y2) * D + x2;
                float lp = logits[off];
                int tag = conn[off];
                float s = 1.0f / (1.0f + expf(lp));   // 1 - sigmoid(lp)
                float w1 = s * s;
                float vf = valid ? 1.0f : 0.0f;
                float sp = fmaxf(-lp, 0.0f) + log1pf(expf(-fabsf(lp)));  // softplus(-lp)
                li = sp * w1 * vf;
                ci = w1 * vf;
                w1s[t] = w1;
                tgf[t] = (float)(valid ? tag : -1);
            }
            for (int o = 32; o; o >>= 1) {
                li += __shfl_down(li, o);
                ci += __shfl_down(ci, o);
            }
            if ((t & 63) == 0) { sred[t >> 6] = li; sred[4 + (t >> 6)] = ci; }
            __syncthreads();
            if (t == 0) {
                atomicAdd(ws + 4 + 2 * level, sred[0] + sred[1] + sred[2] + sred[3]);
                atomicAdd(ws + 5 + 2 * level, sred[4] + sred[5] + sred[6] + sred[7]);
            }
            if (t < 16) {
                int bb = t >> 3, tg = t & 7;
                float mn = INFINITY;
                for (int i = 0; i < 64; ++i) {
                    int j2 = bb * 64 + i;
                    if (tgf[j2] == (float)tg) mn = fminf(mn, w1s[j2]);
                }
                out[6 + level * 16 + bb * 8 + tg] = isinf(mn) ? -1.0f : mn;
            }
            __syncthreads();
        }
    }

    if (accIdx >= 0) {
        for (int o = 32; o; o >>= 1) {
            loss += __shfl_down(loss, o);
            wsum += __shfl_down(wsum, o);
        }
        if ((t & 63) == 0) { sred[t >> 6] = loss; sred[4 + (t >> 6)] = wsum; }
        __syncthreads();
        if (t == 0) {
            float L = sred[0] + sred[1] + sred[2] + sred[3];
            float W = sred[4] + sred[5] + sred[6] + sred[7];
            if (L != 0.0f || W != 0.0f) {
                atomicAdd(ws + accIdx, L);
                atomicAdd(ws + accIdx + 1, W);
            }
        }
    }

    // last-block finalize
    if (t == 0) {
        __threadfence();
        unsigned int old = atomicAdd((unsigned int*)(ws + 8), 1u);
        if (old == NBLK_TOTAL - 1) {
            float s0 = atomicAdd(ws + 0, 0.0f);
            float s1 = atomicAdd(ws + 1, 0.0f);
            float s2 = atomicAdd(ws + 2, 0.0f);
            float s3 = atomicAdd(ws + 3, 0.0f);
            float s4 = atomicAdd(ws + 4, 0.0f);
            float s5 = atomicAdd(ws + 5, 0.0f);
            float s6 = atomicAdd(ws + 6, 0.0f);
            float s7 = atomicAdd(ws + 7, 0.0f);
            out[0] = s4 * 2.0f + s6;   // cls_loss_pos (POS_FACTOR {2,1})
            out[1] = s0 * 2.0f + s2;   // cls_loss_neg (NEG_FACTOR {2,1})
            out[2] = s5 + s7;          // count_pos
            out[3] = s1 + s3;          // count_neg
            out[4] = s5 * 2.0f + s7;   // wsum_pos (anchor factor == 1)
            out[5] = s1 * 2.0f + s3;   // wsum_neg
        }
    }
}

extern "C" void kernel_launch(void* const* d_in, const int* in_sizes, int n_in,
                              void* d_out, int out_size, void* d_ws, size_t ws_size,
                              hipStream_t stream) {
    const float* logits_a = (const float*)d_in[0];
    const float* logits_b = (const float*)d_in[1];
    const float* prob_a   = (const float*)d_in[2];
    const float* prob_b   = (const float*)d_in[3];
    const int*   conn_a   = (const int*)d_in[4];
    const int*   conn_b   = (const int*)d_in[5];
    const int*   coord_a  = (const int*)d_in[6];
    const int*   coord_b  = (const int*)d_in[7];
    float* out = (float*)d_out;
    float* ws  = (float*)d_ws;

    hipMemsetAsync(ws, 0, 12 * sizeof(float), stream);
    fused_kernel<<<NBLK_TOTAL, 256, 0, stream>>>(
        logits_a, logits_b, prob_a, prob_b,
        conn_a, conn_b, coord_a, coord_b, ws, out);
}

// Round 10
// 163.367 us; speedup vs baseline: 1.4040x; 1.4040x over previous
//
#include <hip/hip_runtime.h>
#include <math.h>

// Focal_loss2 — single fused dispatch. R9 = R8-best (rolling y-march, XCD
// swizzle, direct-global loads) + z-PAIRING: one thread emits two z-rows from
// four planes, cutting logical logit traffic 15 -> 10 B/elem (theory: duration
// is proportional to bytes requested past L1 at a fixed per-CU line-service
// rate; every structure R1-R9 converged to ~2.3-2.7 TB/s logical).
//   neg: w = sigmoid(x)^2 * (gt==-1) * (x is 3x3x3 local max); loss += softplus(x)*w
//        local-max test in logit space (monotone sigmoid; validated R3-R9, absmax 0.0)
//   pos: 64 coords/batch/level gather; w1=(1-sigmoid)^2; per-(b,tag) min of w1
// ws (floats): [0]=lossneg_a [1]=wneg_a [2]=lossneg_b [3]=wneg_b
//              [4]=losspos_a [5]=cntpos_a [6]=losspos_b [7]=cntpos_b [8]=block counter
// out: [0]=cls_loss_pos [1]=cls_loss_neg [2]=count_pos [3]=count_neg
//      [4]=wsum_pos [5]=wsum_neg [6..37]=pred_prob_min[2][B=2][T=8]

#define NBLK_A 512    // 4 vol x 8 z-groups(16 z) x 16 y-chunks(8 y)
#define NBLK_B 64     // 4 vol x 2 z-groups(32 z) x  8 y-chunks(8 y)
#define NBLK_TOTAL (NBLK_A + NBLK_B + 1)

using f4 = __attribute__((ext_vector_type(4))) float;

__device__ __forceinline__ float fmax3(float a, float b, float c) {
    return fmaxf(a, fmaxf(b, c));
}

__device__ __forceinline__ f4 fmax3v(f4 a, f4 b, f4 c) {
    f4 r;
    r.x = fmax3(a.x, b.x, c.x); r.y = fmax3(a.y, b.y, c.y);
    r.z = fmax3(a.z, b.z, c.z); r.w = fmax3(a.w, b.w, c.w);
    return r;
}

// Emit one output quad given its z-folded column-max ring (3 y-rows), center
// values and gt. x-halo via wave shuffle (xq in the low lane bits).
template <int XQ>
__device__ __forceinline__ void emit_row(
    const f4 zw0, const f4 zw1, const f4 zw2, const f4 c, const f4 g,
    int xq, float& loss, float& wsum)
{
    f4 cz = fmax3v(zw0, zw1, zw2);                    // y-fold
    float lco = __shfl_up(cz.w, 1);   if (xq == 0)      lco = cz.x;
    float rco = __shfl_down(cz.x, 1); if (xq == XQ - 1) rco = cz.w;
    float ms[4] = {fmax3(lco, cz.x, cz.y), fmax3(cz.x, cz.y, cz.z),
                   fmax3(cz.y, cz.z, cz.w), fmax3(cz.z, cz.w, rco)};
    float cs[4] = {c.x, c.y, c.z, c.w};
    float gs[4] = {g.x, g.y, g.z, g.w};
#pragma unroll
    for (int k = 0; k < 4; ++k) {
        if (gs[k] == -1.0f && ms[k] == cs[k]) {
            float e = __expf(cs[k]);                  // e^x
            float u = __builtin_amdgcn_rcpf(1.0f + e);
            float sc = e * u;                         // sigmoid(x)
            float wv = sc * sc;
            wsum += wv;
            loss += (-__logf(u)) * wv;                // softplus(x)
        }
    }
}

// One thread: fixed (x-quad, z-pair). Marches y0-1..y0+8 (10 rows, clamped),
// emitting 8 y-rows at BOTH z and z+1 from 4 planes z-1..z+2 (z-pairing).
// Boundary: index clamping duplicates an in-window value -> max unchanged.
template <int D, int LOG2D, int XQ>
__device__ __forceinline__ void neg_march2(
    const float* __restrict__ logits, const float* __restrict__ gt,
    int vol, int z, int y0, int xq, float& loss, float& wsum)
{
    const int x0 = xq << 2;
    const float* vb = logits + (vol << (3 * LOG2D));
    const int zm = z > 0 ? z - 1 : 0;              // z+1 <= D-1 by construction
    const int zq = z + 2 < D ? z + 2 : D - 1;
    const float* p0 = vb + (zm << (2 * LOG2D));
    const float* p1 = vb + (z << (2 * LOG2D));
    const float* p2 = vb + ((z + 1) << (2 * LOG2D));
    const float* p3 = vb + (zq << (2 * LOG2D));
    const float* g1 = gt + (vol << (3 * LOG2D)) + (z << (2 * LOG2D));
    const float* g2 = gt + (vol << (3 * LOG2D)) + ((z + 1) << (2 * LOG2D));

    f4 za[3], zb[3];   // rings: z-folded col max for output z / z+1
    f4 ca[2], cb[2];   // rings: center raw quads (plane z / z+1)
    f4 ga[2], gb[2];   // rings: gt quads

#pragma unroll
    for (int s = 0; s < 10; ++s) {
        int yy = y0 - 1 + s;
        yy = yy < 0 ? 0 : (yy > D - 1 ? D - 1 : yy);
        const int ro = (yy << LOG2D) + x0;
        f4 r0 = *(const f4*)(p0 + ro);
        f4 r1 = *(const f4*)(p1 + ro);
        f4 r2 = *(const f4*)(p2 + ro);
        f4 r3 = *(const f4*)(p3 + ro);
        if (s >= 1 && s <= 8) {       // gt rows: single-use stream, bypass L1
            ga[s & 1] = __builtin_nontemporal_load((const f4*)(g1 + ro));
            gb[s & 1] = __builtin_nontemporal_load((const f4*)(g2 + ro));
        }
        za[s % 3] = fmax3v(r0, r1, r2);
        zb[s % 3] = fmax3v(r1, r2, r3);
        ca[s & 1] = r1;
        cb[s & 1] = r2;
        if (s >= 2) {
            emit_row<XQ>(za[0], za[1], za[2], ca[(s - 1) & 1], ga[(s - 1) & 1],
                         xq, loss, wsum);
            emit_row<XQ>(zb[0], zb[1], zb[2], cb[(s - 1) & 1], gb[(s - 1) & 1],
                         xq, loss, wsum);
        }
    }
}

__global__ __launch_bounds__(256, 4) void fused_kernel(
    const float* __restrict__ la, const float* __restrict__ lb,
    const float* __restrict__ ga, const float* __restrict__ gb,
    const int* __restrict__ conn_a, const int* __restrict__ conn_b,
    const int* __restrict__ coord_a, const int* __restrict__ coord_b,
    float* __restrict__ ws, float* __restrict__ out)
{
    __shared__ float sred[8];
    __shared__ float w1s[128];
    __shared__ float tgf[128];
    const int bid = blockIdx.x;
    const int t = threadIdx.x;
    float loss = 0.0f, wsum = 0.0f;
    int accIdx = -1;

    if (bid < NBLK_A) {
        // level a: D=128. xq = t&31, z-pair = t>>5 (block covers 16 z x 8 y).
        // XCD swizzle: xcd = bid&7 owns z-group c (16 z) for all 4 vols,
        // y-chunks swept fastest.
        accIdx = 0;
        const int c = bid & 7;         // XCD id == z-group
        const int g = bid >> 3;        // 0..63
        const int yc = g & 15;         // y fastest
        const int vol = g >> 4;        // 0..3
        neg_march2<128, 7, 32>(la, ga, vol, c * 16 + (t >> 5) * 2, yc * 8,
                               t & 31, loss, wsum);
    } else if (bid < NBLK_A + NBLK_B) {
        // level b: D=64. xq = t&15, z-pair = t>>4 (block covers 32 z x 8 y).
        accIdx = 2;
        const int b2 = bid - NBLK_A;
        const int c = b2 & 7;          // XCD owns (vol = c>>1, zg = c&1)
        const int yc = b2 >> 3;        // 0..7
        const int vol = c >> 1;
        const int zg = c & 1;
        neg_march2<64, 6, 16>(lb, gb, vol, zg * 32 + (t >> 4) * 2, yc * 8,
                              t & 15, loss, wsum);
    } else {
        // pos block: both levels, 128 active threads
        for (int level = 0; level < 2; ++level) {
            const float* logits = level ? lb : la;
            const int* conn = level ? conn_b : conn_a;
            const int* coord = level ? coord_b : coord_a;
            const int D = level ? 64 : 128;
            float li = 0.0f, ci = 0.0f;
            if (t < 128) {
                const int* c4 = coord + t * 4;
                int a = c4[0], zz = c4[1], yy = c4[2], xx = c4[3];
                bool valid = a > -1;
                int aa = valid ? a : 0, z2 = valid ? zz : 0,
                    y2 = valid ? yy : 0, x2 = valid ? xx : 0;
                int b = t >> 6;
                int off = (((b * 2 + aa) * D + z2) * D + y2) * D + x2;
                float lp = logits[off];
                int tag = conn[off];
                float s = 1.0f / (1.0f + expf(lp));   // 1 - sigmoid(lp)
                float w1 = s * s;
                float vf = valid ? 1.0f : 0.0f;
                float sp = fmaxf(-lp, 0.0f) + log1pf(expf(-fabsf(lp)));  // softplus(-lp)
                li = sp * w1 * vf;
                ci = w1 * vf;
                w1s[t] = w1;
                tgf[t] = (float)(valid ? tag : -1);
            }
            for (int o = 32; o; o >>= 1) {
                li += __shfl_down(li, o);
                ci += __shfl_down(ci, o);
            }
            if ((t & 63) == 0) { sred[t >> 6] = li; sred[4 + (t >> 6)] = ci; }
            __syncthreads();
            if (t == 0) {
                atomicAdd(ws + 4 + 2 * level, sred[0] + sred[1] + sred[2] + sred[3]);
                atomicAdd(ws + 5 + 2 * level, sred[4] + sred[5] + sred[6] + sred[7]);
            }
            if (t < 16) {
                int bb = t >> 3, tg = t & 7;
                float mn = INFINITY;
                for (int i = 0; i < 64; ++i) {
                    int j = bb * 64 + i;
                    if (tgf[j] == (float)tg) mn = fminf(mn, w1s[j]);
                }
                out[6 + level * 16 + bb * 8 + tg] = isinf(mn) ? -1.0f : mn;
            }
            __syncthreads();
        }
    }

    if (accIdx >= 0) {
        for (int o = 32; o; o >>= 1) {
            loss += __shfl_down(loss, o);
            wsum += __shfl_down(wsum, o);
        }
        if ((t & 63) == 0) { sred[t >> 6] = loss; sred[4 + (t >> 6)] = wsum; }
        __syncthreads();
        if (t == 0) {
            float L = sred[0] + sred[1] + sred[2] + sred[3];
            float W = sred[4] + sred[5] + sred[6] + sred[7];
            if (L != 0.0f || W != 0.0f) {
                atomicAdd(ws + accIdx, L);
                atomicAdd(ws + accIdx + 1, W);
            }
        }
    }

    // last-block finalize
    if (t == 0) {
        __threadfence();
        unsigned int old = atomicAdd((unsigned int*)(ws + 8), 1u);
        if (old == NBLK_TOTAL - 1) {
            float s0 = atomicAdd(ws + 0, 0.0f);
            float s1 = atomicAdd(ws + 1, 0.0f);
            float s2 = atomicAdd(ws + 2, 0.0f);
            float s3 = atomicAdd(ws + 3, 0.0f);
            float s4 = atomicAdd(ws + 4, 0.0f);
            float s5 = atomicAdd(ws + 5, 0.0f);
            float s6 = atomicAdd(ws + 6, 0.0f);
            float s7 = atomicAdd(ws + 7, 0.0f);
            out[0] = s4 * 2.0f + s6;   // cls_loss_pos (POS_FACTOR {2,1})
            out[1] = s0 * 2.0f + s2;   // cls_loss_neg (NEG_FACTOR {2,1})
            out[2] = s5 + s7;          // count_pos
            out[3] = s1 + s3;          // count_neg
            out[4] = s5 * 2.0f + s7;   // wsum_pos (anchor factor == 1)
            out[5] = s1 * 2.0f + s3;   // wsum_neg
        }
    }
}

extern "C" void kernel_launch(void* const* d_in, const int* in_sizes, int n_in,
                              void* d_out, int out_size, void* d_ws, size_t ws_size,
                              hipStream_t stream) {
    const float* logits_a = (const float*)d_in[0];
    const float* logits_b = (const float*)d_in[1];
    const float* prob_a   = (const float*)d_in[2];
    const float* prob_b   = (const float*)d_in[3];
    const int*   conn_a   = (const int*)d_in[4];
    const int*   conn_b   = (const int*)d_in[5];
    const int*   coord_a  = (const int*)d_in[6];
    const int*   coord_b  = (const int*)d_in[7];
    float* out = (float*)d_out;
    float* ws  = (float*)d_ws;

    hipMemsetAsync(ws, 0, 12 * sizeof(float), stream);
    fused_kernel<<<NBLK_TOTAL, 256, 0, stream>>>(
        logits_a, logits_b, prob_a, prob_b,
        conn_a, conn_b, coord_a, coord_b, ws, out);
}